// Round 1
// baseline (429.918 us; speedup 1.0000x reference)
//
#include <hip/hip_runtime.h>
#include <hip/hip_bf16.h>

#define B_ 2
#define N_ 4096
#define D_ 1024
#define H_ 16
#define GH_ 8
#define DH_ 64
#define M_ 256
#define W_ 256
#define NW_ 16
#define EPS_ 1e-4f
#define RATIO_ 0.0625f
#define R_ (B_*N_)

typedef __attribute__((ext_vector_type(8))) short short8;
typedef __attribute__((ext_vector_type(4))) float float4_;

__device__ __forceinline__ float b2f(unsigned short u){
  union { unsigned int i; float f; } x; x.i = ((unsigned int)u) << 16; return x.f;
}
__device__ __forceinline__ unsigned short f2b(float f){
  unsigned int u = __float_as_uint(f);
  u = u + 0x7FFFu + ((u >> 16) & 1u);
  return (unsigned short)(u >> 16);
}
__device__ __forceinline__ unsigned int encf(float x){
  unsigned int u = __float_as_uint(x);
  return (u & 0x80000000u) ? ~u : (u | 0x80000000u);
}
__device__ __forceinline__ float decf(unsigned int e){
  unsigned int u = (e & 0x80000000u) ? (e ^ 0x80000000u) : ~e;
  return __uint_as_float(u);
}

// ---------------------------------------------------------------- init / casts
__global__ void init_misc(unsigned int* stab_enc){
  if (threadIdx.x == 0) *stab_enc = encf(-3.0e38f);
}

__global__ void cast_f32_bf16(const float* __restrict__ src, unsigned short* __restrict__ dst, int n8){
  int i = blockIdx.x*256 + threadIdx.x;
  if (i >= n8) return;
  const float4_* sp = (const float4_*)src + (size_t)i*2;
  float4_ a = sp[0], b = sp[1];
  short8 o;
  o[0]=(short)f2b(a[0]); o[1]=(short)f2b(a[1]); o[2]=(short)f2b(a[2]); o[3]=(short)f2b(a[3]);
  o[4]=(short)f2b(b[0]); o[5]=(short)f2b(b[1]); o[6]=(short)f2b(b[2]); o[7]=(short)f2b(b[3]);
  *((short8*)dst + i) = o;
}

// proj [M][DH] f32 -> bf16 with dn = 64^-0.25 folded in
__global__ void cast_proj(const float* __restrict__ proj, unsigned short* __restrict__ projb){
  int i = blockIdx.x*256 + threadIdx.x;
  if (i < M_*DH_) projb[i] = f2b(proj[i]*0.35355339059327373f);
}

// W [K][N] f32 -> Wt [N][K] bf16 (so GEMM B-operand reads are k-contiguous)
__global__ void transpose_w(const float* w0, const float* w1, const float* w2, const float* w3,
                            unsigned short* t0, unsigned short* t1, unsigned short* t2, unsigned short* t3){
  const float* src; unsigned short* dst;
  switch (blockIdx.z){
    case 0: src = w0; dst = t0; break;
    case 1: src = w1; dst = t1; break;
    case 2: src = w2; dst = t2; break;
    default: src = w3; dst = t3; break;
  }
  __shared__ float tile[64][65];
  int r0 = blockIdx.x*64, c0 = blockIdx.y*64;
  for (int it = 0; it < 16; ++it){
    int idx = it*256 + threadIdx.x;
    int r = idx >> 6, c = idx & 63;
    tile[r][c] = src[(size_t)(r0 + r)*D_ + c0 + c];
  }
  __syncthreads();
  for (int it = 0; it < 16; ++it){
    int idx = it*256 + threadIdx.x;
    int r = idx >> 6, c = idx & 63;
    dst[(size_t)(c0 + r)*D_ + r0 + c] = f2b(tile[c][r]);
  }
}

// ---------------------------------------------------------------- GEMM (A row-major bf16, Bt = B^T row-major bf16)
template<int FINAL>
__launch_bounds__(256)
__global__ void gemm_bf16(const unsigned short* __restrict__ A, const unsigned short* __restrict__ Bt,
                          unsigned short* __restrict__ Cb, float* __restrict__ Cf,
                          const float* __restrict__ bias, int K, int Ncols){
  __shared__ __attribute__((aligned(16))) unsigned short As[128*40];
  __shared__ __attribute__((aligned(16))) unsigned short Bs[128*40];
  int tid = threadIdx.x, lane = tid & 63, wave = tid >> 6;
  int bm = blockIdx.x*128, bn = blockIdx.y*128;
  int wm = (wave >> 1)*64, wn = (wave & 1)*64;
  float4_ acc[4][4];
  #pragma unroll
  for (int i = 0; i < 4; ++i)
    #pragma unroll
    for (int j = 0; j < 4; ++j)
      #pragma unroll
      for (int r = 0; r < 4; ++r) acc[i][j][r] = 0.f;
  int ar = tid >> 2, ac = (tid & 3)*8;
  int kk = (lane >> 4)*8;
  for (int k0 = 0; k0 < K; k0 += 32){
    short8 va0 = *(const short8*)&A[(size_t)(bm + ar)*K + k0 + ac];
    short8 va1 = *(const short8*)&A[(size_t)(bm + ar + 64)*K + k0 + ac];
    short8 vb0 = *(const short8*)&Bt[(size_t)(bn + ar)*K + k0 + ac];
    short8 vb1 = *(const short8*)&Bt[(size_t)(bn + ar + 64)*K + k0 + ac];
    *(short8*)&As[ar*40 + ac] = va0;
    *(short8*)&As[(ar + 64)*40 + ac] = va1;
    *(short8*)&Bs[ar*40 + ac] = vb0;
    *(short8*)&Bs[(ar + 64)*40 + ac] = vb1;
    __syncthreads();
    short8 af[4], bf[4];
    #pragma unroll
    for (int i = 0; i < 4; ++i) af[i] = *(const short8*)&As[(wm + i*16 + (lane&15))*40 + kk];
    #pragma unroll
    for (int j = 0; j < 4; ++j) bf[j] = *(const short8*)&Bs[(wn + j*16 + (lane&15))*40 + kk];
    #pragma unroll
    for (int i = 0; i < 4; ++i)
      #pragma unroll
      for (int j = 0; j < 4; ++j)
        acc[i][j] = __builtin_amdgcn_mfma_f32_16x16x32_bf16(af[i], bf[j], acc[i][j], 0, 0, 0);
    __syncthreads();
  }
  int rr = (lane >> 4)*4, cc = lane & 15;
  #pragma unroll
  for (int i = 0; i < 4; ++i)
    #pragma unroll
    for (int j = 0; j < 4; ++j)
      #pragma unroll
      for (int r = 0; r < 4; ++r){
        size_t row = bm + wm + i*16 + rr + r;
        int col = bn + wn + j*16 + cc;
        if (FINAL) Cf[row*Ncols + col] = acc[i][j][r] + bias[col];
        else       Cb[row*Ncols + col] = f2b(acc[i][j][r]);
      }
}

// ---------------------------------------------------------------- phi kernels (MODE 0=query, 1=key max pass, 2=key phi pass)
template<int MODE>
__launch_bounds__(256)
__global__ void phi_kernel(const unsigned short* __restrict__ QK, const unsigned short* __restrict__ projb,
                           unsigned short* __restrict__ phi, unsigned int* __restrict__ stab_enc){
  int tid = threadIdx.x, lane = tid & 63, wave = tid >> 6;
  int h = blockIdx.y, b = blockIdx.z;
  int n0 = blockIdx.x*64;
  int col0 = h*64;
  int kk = (lane >> 4)*8;
  size_t rowbase = (size_t)b*N_ + n0 + wave*16;
  short8 qa[2];
  #pragma unroll
  for (int ks = 0; ks < 2; ++ks)
    qa[ks] = *(const short8*)&QK[(rowbase + (lane&15))*D_ + col0 + ks*32 + kk];
  __shared__ float lds_diag[4][16];
  if (MODE != 1){
    float s = 0.f;
    #pragma unroll
    for (int ks = 0; ks < 2; ++ks)
      #pragma unroll
      for (int j = 0; j < 8; ++j){ float q = b2f((unsigned short)qa[ks][j]); s += q*q; }
    s += __shfl_xor(s, 16, 64);
    s += __shfl_xor(s, 32, 64);
    s *= 0.0625f;   // 0.5 * dn^2
    if (lane < 16) lds_diag[wave][lane] = s;
  }
  float4_ dd[16];
  #pragma unroll
  for (int mt = 0; mt < 16; ++mt){
    float4_ a; a[0]=a[1]=a[2]=a[3]=0.f;
    #pragma unroll
    for (int ks = 0; ks < 2; ++ks){
      short8 bfr = *(const short8*)&projb[(size_t)(mt*16 + (lane&15))*DH_ + ks*32 + kk];
      a = __builtin_amdgcn_mfma_f32_16x16x32_bf16(qa[ks], bfr, a, 0, 0, 0);
    }
    dd[mt] = a;
  }
  if (MODE == 1){
    float mx = -3e38f;
    #pragma unroll
    for (int mt = 0; mt < 16; ++mt)
      #pragma unroll
      for (int r = 0; r < 4; ++r) mx = fmaxf(mx, dd[mt][r]);
    #pragma unroll
    for (int m = 1; m < 64; m <<= 1) mx = fmaxf(mx, __shfl_xor(mx, m, 64));
    if (lane == 0) atomicMax(stab_enc, encf(mx));
    return;
  }
  float stab[4];
  if (MODE == 0){
    #pragma unroll
    for (int r = 0; r < 4; ++r){
      float mx = dd[0][r];
      #pragma unroll
      for (int mt = 1; mt < 16; ++mt) mx = fmaxf(mx, dd[mt][r]);
      mx = fmaxf(mx, __shfl_xor(mx, 1, 64));
      mx = fmaxf(mx, __shfl_xor(mx, 2, 64));
      mx = fmaxf(mx, __shfl_xor(mx, 4, 64));
      mx = fmaxf(mx, __shfl_xor(mx, 8, 64));
      stab[r] = mx;
    }
  } else {
    float s = decf(*stab_enc);
    #pragma unroll
    for (int r = 0; r < 4; ++r) stab[r] = s;
  }
  __syncthreads();
  float dg[4];
  #pragma unroll
  for (int r = 0; r < 4; ++r) dg[r] = lds_diag[wave][(lane>>4)*4 + r];
  size_t phibase = (size_t)(b*GH_ + h)*N_ + n0 + wave*16;
  #pragma unroll
  for (int mt = 0; mt < 16; ++mt)
    #pragma unroll
    for (int r = 0; r < 4; ++r){
      float v = RATIO_*(__expf(dd[mt][r] - dg[r] - stab[r]) + EPS_);
      phi[(phibase + (lane>>4)*4 + r)*M_ + mt*16 + (lane&15)] = f2b(v);
    }
}

// ---------------------------------------------------------------- k_sum
__global__ void ksum_kernel(const unsigned short* __restrict__ phi_k, float* __restrict__ k_sum){
  int tid = threadIdx.x;
  int h = blockIdx.y, b = blockIdx.z, split = blockIdx.x;
  int bh = b*GH_ + h;
  size_t base = ((size_t)bh*N_ + split*512)*M_ + tid;
  float s = 0.f;
  for (int n = 0; n < 512; ++n) s += b2f(phi_k[base + (size_t)n*M_]);
  atomicAdd(&k_sum[bh*M_ + tid], s);
}

// ---------------------------------------------------------------- ctx = phi_k^T @ V  (per b,h; split over n, f32 atomics)
__launch_bounds__(256)
__global__ void ctx_kernel(const unsigned short* __restrict__ phi_k, const unsigned short* __restrict__ Vb,
                           float* __restrict__ ctx){
  __shared__ __attribute__((aligned(16))) unsigned short pt[256*72];
  __shared__ __attribute__((aligned(16))) unsigned short vt[64*72];
  int tid = threadIdx.x, lane = tid & 63, wave = tid >> 6;
  int h = blockIdx.y, b = blockIdx.z, split = blockIdx.x;
  int bh = b*GH_ + h;
  int col0 = h*64;
  int kk = (lane >> 4)*8;
  float4_ acc[4][4];
  #pragma unroll
  for (int i = 0; i < 4; ++i)
    #pragma unroll
    for (int j = 0; j < 4; ++j)
      #pragma unroll
      for (int r = 0; r < 4; ++r) acc[i][j][r] = 0.f;
  for (int c = 0; c < 4; ++c){
    int n0 = split*256 + c*64;
    __syncthreads();
    {
      int m8 = (tid & 31)*8, nb = tid >> 5;
      for (int i = 0; i < 8; ++i){
        int n = nb + i*8;
        short8 v = *(const short8*)&phi_k[((size_t)bh*N_ + n0 + n)*M_ + m8];
        #pragma unroll
        for (int j = 0; j < 8; ++j) pt[(m8 + j)*72 + n] = (unsigned short)v[j];
      }
      int d8 = (tid & 7)*8, nb2 = tid >> 3;
      for (int i = 0; i < 2; ++i){
        int n = nb2 + i*32;
        short8 v = *(const short8*)&Vb[((size_t)b*N_ + n0 + n)*D_ + col0 + d8];
        #pragma unroll
        for (int j = 0; j < 8; ++j) vt[(d8 + j)*72 + n] = (unsigned short)v[j];
      }
    }
    __syncthreads();
    #pragma unroll
    for (int ks = 0; ks < 2; ++ks){
      short8 af[4], bf[4];
      #pragma unroll
      for (int mt = 0; mt < 4; ++mt) af[mt] = *(const short8*)&pt[(wave*64 + mt*16 + (lane&15))*72 + ks*32 + kk];
      #pragma unroll
      for (int dt = 0; dt < 4; ++dt) bf[dt] = *(const short8*)&vt[(dt*16 + (lane&15))*72 + ks*32 + kk];
      #pragma unroll
      for (int mt = 0; mt < 4; ++mt)
        #pragma unroll
        for (int dt = 0; dt < 4; ++dt)
          acc[mt][dt] = __builtin_amdgcn_mfma_f32_16x16x32_bf16(af[mt], bf[dt], acc[mt][dt], 0, 0, 0);
    }
  }
  int rr = (lane >> 4)*4, cc = lane & 15;
  #pragma unroll
  for (int mt = 0; mt < 4; ++mt)
    #pragma unroll
    for (int dt = 0; dt < 4; ++dt)
      #pragma unroll
      for (int r = 0; r < 4; ++r){
        int m = wave*64 + mt*16 + rr + r;
        int d = dt*16 + cc;
        atomicAdd(&ctx[((size_t)bh*M_ + m)*DH_ + d], acc[mt][dt][r]);
      }
}

// ctx f32 [bh][m][d] -> ctxbT bf16 [bh][d][m]
__global__ void ctx_cast(const float* __restrict__ ctx, unsigned short* __restrict__ ctxbT){
  int idx = blockIdx.x*256 + threadIdx.x;
  int bh = idx >> 14, rem = idx & 16383;
  int m = rem >> 6, d = rem & 63;
  ctxbT[((size_t)bh*DH_ + d)*M_ + m] = f2b(ctx[idx]);
}

// ---------------------------------------------------------------- out_g = (phi_q @ ctx) * d_inv
__launch_bounds__(256)
__global__ void outg_kernel(const unsigned short* __restrict__ phi_q, const unsigned short* __restrict__ ctxbT,
                            const float* __restrict__ k_sum, unsigned short* __restrict__ attnb){
  __shared__ float ks_l[256];
  __shared__ float dpart[64][4];
  __shared__ float dinv[64];
  int tid = threadIdx.x, lane = tid & 63, wave = tid >> 6;
  int h = blockIdx.y, b = blockIdx.z;
  int n0 = blockIdx.x*64;
  int bh = b*GH_ + h;
  ks_l[tid] = k_sum[bh*M_ + tid];
  __syncthreads();
  {
    int row = tid >> 2, q = tid & 3;
    const unsigned short* pr = &phi_q[((size_t)bh*N_ + n0 + row)*M_ + q*64];
    float s = 0.f;
    for (int m = 0; m < 64; ++m) s += b2f(pr[m])*ks_l[q*64 + m];
    dpart[row][q] = s;
  }
  __syncthreads();
  if (tid < 64) dinv[tid] = 1.f/(dpart[tid][0] + dpart[tid][1] + dpart[tid][2] + dpart[tid][3]);
  __syncthreads();
  int kk = (lane >> 4)*8;
  float4_ acc[4];
  #pragma unroll
  for (int dt = 0; dt < 4; ++dt){ acc[dt][0]=acc[dt][1]=acc[dt][2]=acc[dt][3]=0.f; }
  size_t arow = ((size_t)bh*N_ + n0 + wave*16 + (lane&15))*M_;
  #pragma unroll
  for (int ks = 0; ks < 8; ++ks){
    short8 af = *(const short8*)&phi_q[arow + ks*32 + kk];
    #pragma unroll
    for (int dt = 0; dt < 4; ++dt){
      short8 bf = *(const short8*)&ctxbT[((size_t)bh*DH_ + dt*16 + (lane&15))*M_ + ks*32 + kk];
      acc[dt] = __builtin_amdgcn_mfma_f32_16x16x32_bf16(af, bf, acc[dt], 0, 0, 0);
    }
  }
  int rr = (lane >> 4)*4, cc = lane & 15;
  #pragma unroll
  for (int dt = 0; dt < 4; ++dt)
    #pragma unroll
    for (int r = 0; r < 4; ++r){
      int rloc = wave*16 + rr + r;
      float o = acc[dt][r]*dinv[rloc];
      attnb[((size_t)b*N_ + n0 + rloc)*D_ + h*64 + dt*16 + cc] = f2b(o);
    }
}

// ---------------------------------------------------------------- local windowed attention (flash-style over <=3 windows)
__launch_bounds__(256)
__global__ void local_attn_kernel(const unsigned short* __restrict__ Qb, const unsigned short* __restrict__ Kb,
                                  const unsigned short* __restrict__ Vb, unsigned short* __restrict__ attnb){
  __shared__ __attribute__((aligned(16))) unsigned short vt[64*72];
  __shared__ __attribute__((aligned(16))) unsigned short pl[4][16*72];
  int tid = threadIdx.x, lane = tid & 63, wave = tid >> 6;
  int qt = blockIdx.x, w = blockIdx.y, z = blockIdx.z;
  int b = z >> 3, hl = z & 7;
  int col0 = (GH_ + hl)*64;
  int q0 = w*W_ + qt*64;
  int kk = (lane >> 4)*8;
  short8 qa[2];
  #pragma unroll
  for (int ks = 0; ks < 2; ++ks){
    short8 v = *(const short8*)&Qb[((size_t)b*N_ + q0 + wave*16 + (lane&15))*D_ + col0 + ks*32 + kk];
    #pragma unroll
    for (int j = 0; j < 8; ++j) v[j] = (short)f2b(b2f((unsigned short)v[j])*0.125f);
    qa[ks] = v;
  }
  float m_r[4], l_r[4];
  float4_ accv[4];
  #pragma unroll
  for (int r = 0; r < 4; ++r){ m_r[r] = -1e30f; l_r[r] = 0.f; }
  #pragma unroll
  for (int dt = 0; dt < 4; ++dt){ accv[dt][0]=accv[dt][1]=accv[dt][2]=accv[dt][3]=0.f; }
  for (int wi = w - 1; wi <= w + 1; ++wi){
    if (wi < 0 || wi >= NW_) continue;
    for (int c = 0; c < 4; ++c){
      int key0 = wi*W_ + c*64;
      __syncthreads();
      {
        int d8 = (tid & 7)*8, nb = tid >> 3;
        for (int i = 0; i < 2; ++i){
          int kkey = nb + i*32;
          short8 v = *(const short8*)&Vb[((size_t)b*N_ + key0 + kkey)*D_ + col0 + d8];
          #pragma unroll
          for (int j = 0; j < 8; ++j) vt[(d8 + j)*72 + kkey] = (unsigned short)v[j];
        }
      }
      float4_ s[4];
      #pragma unroll
      for (int kt = 0; kt < 4; ++kt){ s[kt][0]=s[kt][1]=s[kt][2]=s[kt][3]=0.f; }
      #pragma unroll
      for (int ks = 0; ks < 2; ++ks)
        #pragma unroll
        for (int kt = 0; kt < 4; ++kt){
          short8 kb = *(const short8*)&Kb[((size_t)b*N_ + key0 + kt*16 + (lane&15))*D_ + col0 + ks*32 + kk];
          s[kt] = __builtin_amdgcn_mfma_f32_16x16x32_bf16(qa[ks], kb, s[kt], 0, 0, 0);
        }
      float p[4][4];
      #pragma unroll
      for (int r = 0; r < 4; ++r){
        float mx = fmaxf(fmaxf(s[0][r], s[1][r]), fmaxf(s[2][r], s[3][r]));
        mx = fmaxf(mx, __shfl_xor(mx, 1, 64));
        mx = fmaxf(mx, __shfl_xor(mx, 2, 64));
        mx = fmaxf(mx, __shfl_xor(mx, 4, 64));
        mx = fmaxf(mx, __shfl_xor(mx, 8, 64));
        float mn = fmaxf(m_r[r], mx);
        float alpha = __expf(m_r[r] - mn);
        m_r[r] = mn;
        #pragma unroll
        for (int kt = 0; kt < 4; ++kt) p[kt][r] = __expf(s[kt][r] - mn);
        float rs = p[0][r] + p[1][r] + p[2][r] + p[3][r];
        rs += __shfl_xor(rs, 1, 64);
        rs += __shfl_xor(rs, 2, 64);
        rs += __shfl_xor(rs, 4, 64);
        rs += __shfl_xor(rs, 8, 64);
        l_r[r] = l_r[r]*alpha + rs;
        #pragma unroll
        for (int dt = 0; dt < 4; ++dt) accv[dt][r] *= alpha;
      }
      int rr = (lane >> 4)*4, cc = lane & 15;
      #pragma unroll
      for (int kt = 0; kt < 4; ++kt)
        #pragma unroll
        for (int r = 0; r < 4; ++r)
          pl[wave][(rr + r)*72 + kt*16 + cc] = f2b(p[kt][r]);
      __syncthreads();
      #pragma unroll
      for (int ks = 0; ks < 2; ++ks){
        short8 pa = *(const short8*)&pl[wave][(lane&15)*72 + ks*32 + kk];
        #pragma unroll
        for (int dt = 0; dt < 4; ++dt){
          short8 vb = *(const short8*)&vt[(dt*16 + (lane&15))*72 + ks*32 + kk];
          accv[dt] = __builtin_amdgcn_mfma_f32_16x16x32_bf16(pa, vb, accv[dt], 0, 0, 0);
        }
      }
    }
  }
  int rr = (lane >> 4)*4, cc = lane & 15;
  #pragma unroll
  for (int dt = 0; dt < 4; ++dt)
    #pragma unroll
    for (int r = 0; r < 4; ++r){
      int rloc = wave*16 + rr + r;
      float o = accv[dt][r]/l_r[r];
      attnb[((size_t)b*N_ + q0 + rloc)*D_ + col0 + dt*16 + cc] = f2b(o);
    }
}

// ---------------------------------------------------------------- host launch
extern "C" void kernel_launch(void* const* d_in, const int* in_sizes, int n_in,
                              void* d_out, int out_size, void* d_ws, size_t ws_size,
                              hipStream_t stream){
  const float* x    = (const float*)d_in[0];
  const float* Wq   = (const float*)d_in[1];
  const float* Wk   = (const float*)d_in[2];
  const float* Wv   = (const float*)d_in[3];
  const float* Wo   = (const float*)d_in[4];
  const float* bo   = (const float*)d_in[5];
  const float* proj = (const float*)d_in[6];
  float* out = (float*)d_out;
  char* ws = (char*)d_ws;

  const size_t o_Wqt  = 0;
  const size_t o_Wkt  = o_Wqt  + (size_t)D_*D_*2;
  const size_t o_Wvt  = o_Wkt  + (size_t)D_*D_*2;
  const size_t o_Wot  = o_Wvt  + (size_t)D_*D_*2;
  const size_t o_Xb   = o_Wot  + (size_t)D_*D_*2;        // reused as attnb
  const size_t o_Qb   = o_Xb   + (size_t)R_*D_*2;
  const size_t o_Kb   = o_Qb   + (size_t)R_*D_*2;
  const size_t o_Vb   = o_Kb   + (size_t)R_*D_*2;
  const size_t o_phiq = o_Vb   + (size_t)R_*D_*2;
  const size_t o_phik = o_phiq + (size_t)B_*GH_*N_*M_*2;
  const size_t o_ctx  = o_phik + (size_t)B_*GH_*N_*M_*2;
  const size_t o_ksum = o_ctx  + (size_t)B_*GH_*M_*DH_*4;
  const size_t o_ctxT = o_ksum + (size_t)B_*GH_*M_*4;
  const size_t o_projb= o_ctxT + (size_t)B_*GH_*M_*DH_*2;
  const size_t o_stab = o_projb+ (size_t)M_*DH_*2;

  unsigned short* Wqt  = (unsigned short*)(ws + o_Wqt);
  unsigned short* Wkt  = (unsigned short*)(ws + o_Wkt);
  unsigned short* Wvt  = (unsigned short*)(ws + o_Wvt);
  unsigned short* Wot  = (unsigned short*)(ws + o_Wot);
  unsigned short* Xb   = (unsigned short*)(ws + o_Xb);
  unsigned short* attnb= Xb;
  unsigned short* Qb   = (unsigned short*)(ws + o_Qb);
  unsigned short* Kb   = (unsigned short*)(ws + o_Kb);
  unsigned short* Vb   = (unsigned short*)(ws + o_Vb);
  unsigned short* phiq = (unsigned short*)(ws + o_phiq);
  unsigned short* phik = (unsigned short*)(ws + o_phik);
  float*          ctxf = (float*)(ws + o_ctx);
  float*          ksum = (float*)(ws + o_ksum);
  unsigned short* ctxT = (unsigned short*)(ws + o_ctxT);
  unsigned short* projb= (unsigned short*)(ws + o_projb);
  unsigned int*   stab = (unsigned int*)(ws + o_stab);

  (void)in_sizes; (void)n_in; (void)out_size; (void)ws_size;

  // zero ctx accumulator + k_sum (contiguous)
  (void)hipMemsetAsync(ws + o_ctx, 0, (size_t)B_*GH_*M_*DH_*4 + (size_t)B_*GH_*M_*4, stream);
  init_misc<<<1, 1, 0, stream>>>(stab);
  cast_f32_bf16<<<R_*D_/8/256, 256, 0, stream>>>(x, Xb, R_*D_/8);
  cast_proj<<<64, 256, 0, stream>>>(proj, projb);
  transpose_w<<<dim3(16,16,4), 256, 0, stream>>>(Wq, Wk, Wv, Wo, Wqt, Wkt, Wvt, Wot);

  gemm_bf16<0><<<dim3(64,8), 256, 0, stream>>>(Xb, Wqt, Qb, nullptr, nullptr, D_, D_);
  gemm_bf16<0><<<dim3(64,8), 256, 0, stream>>>(Xb, Wkt, Kb, nullptr, nullptr, D_, D_);
  gemm_bf16<0><<<dim3(64,8), 256, 0, stream>>>(Xb, Wvt, Vb, nullptr, nullptr, D_, D_);

  phi_kernel<0><<<dim3(64,8,2), 256, 0, stream>>>(Qb, projb, phiq, stab);
  phi_kernel<1><<<dim3(64,8,2), 256, 0, stream>>>(Kb, projb, phik, stab);
  phi_kernel<2><<<dim3(64,8,2), 256, 0, stream>>>(Kb, projb, phik, stab);

  ksum_kernel<<<dim3(8,8,2), 256, 0, stream>>>(phik, ksum);
  ctx_kernel<<<dim3(16,8,2), 256, 0, stream>>>(phik, Vb, ctxf);
  ctx_cast<<<1024, 256, 0, stream>>>(ctxf, ctxT);
  outg_kernel<<<dim3(64,8,2), 256, 0, stream>>>(phiq, ctxT, ksum, attnb);
  local_attn_kernel<<<dim3(4,16,16), 256, 0, stream>>>(Qb, Kb, Vb, attnb);

  gemm_bf16<1><<<dim3(64,8), 256, 0, stream>>>(attnb, Wot, nullptr, out, bo, D_, D_);
}

// Round 2
// 429.663 us; speedup vs baseline: 1.0006x; 1.0006x over previous
//
#include <hip/hip_runtime.h>
#include <hip/hip_bf16.h>

#define B_ 2
#define N_ 4096
#define D_ 1024
#define H_ 16
#define GH_ 8
#define DH_ 64
#define M_ 256
#define W_ 256
#define NW_ 16
#define EPS_ 1e-4f
#define RATIO_ 0.0625f
#define R_ (B_*N_)

typedef __attribute__((ext_vector_type(8))) short short8;
typedef __attribute__((ext_vector_type(4))) float float4_;

__device__ __forceinline__ float b2f(unsigned short u){
  union { unsigned int i; float f; } x; x.i = ((unsigned int)u) << 16; return x.f;
}
__device__ __forceinline__ unsigned short f2b(float f){
  unsigned int u = __float_as_uint(f);
  u = u + 0x7FFFu + ((u >> 16) & 1u);
  return (unsigned short)(u >> 16);
}
__device__ __forceinline__ unsigned int encf(float x){
  unsigned int u = __float_as_uint(x);
  return (u & 0x80000000u) ? ~u : (u | 0x80000000u);
}
__device__ __forceinline__ float decf(unsigned int e){
  unsigned int u = (e & 0x80000000u) ? (e ^ 0x80000000u) : ~e;
  return __uint_as_float(u);
}
__device__ __forceinline__ void gl_lds16(const unsigned short* g, unsigned short* l){
  __builtin_amdgcn_global_load_lds((const __attribute__((address_space(1))) unsigned int*)g,
                                   (__attribute__((address_space(3))) unsigned int*)l, 16, 0, 0);
}

// ---------------------------------------------------------------- init / casts
__global__ void init_misc(unsigned int* stab_enc){
  if (threadIdx.x == 0) *stab_enc = encf(-3.0e38f);
}

__global__ void cast_f32_bf16(const float* __restrict__ src, unsigned short* __restrict__ dst, int n8){
  int i = blockIdx.x*256 + threadIdx.x;
  if (i >= n8) return;
  const float4_* sp = (const float4_*)src + (size_t)i*2;
  float4_ a = sp[0], b = sp[1];
  short8 o;
  o[0]=(short)f2b(a[0]); o[1]=(short)f2b(a[1]); o[2]=(short)f2b(a[2]); o[3]=(short)f2b(a[3]);
  o[4]=(short)f2b(b[0]); o[5]=(short)f2b(b[1]); o[6]=(short)f2b(b[2]); o[7]=(short)f2b(b[3]);
  *((short8*)dst + i) = o;
}

__global__ void cast_proj(const float* __restrict__ proj, unsigned short* __restrict__ projb){
  int i = blockIdx.x*256 + threadIdx.x;
  if (i < M_*DH_) projb[i] = f2b(proj[i]*0.35355339059327373f);
}

__global__ void transpose_w(const float* w0, const float* w1, const float* w2, const float* w3,
                            unsigned short* t0, unsigned short* t1, unsigned short* t2, unsigned short* t3){
  const float* src; unsigned short* dst;
  switch (blockIdx.z){
    case 0: src = w0; dst = t0; break;
    case 1: src = w1; dst = t1; break;
    case 2: src = w2; dst = t2; break;
    default: src = w3; dst = t3; break;
  }
  __shared__ float tile[64][65];
  int r0 = blockIdx.x*64, c0 = blockIdx.y*64;
  for (int it = 0; it < 16; ++it){
    int idx = it*256 + threadIdx.x;
    int r = idx >> 6, c = idx & 63;
    tile[r][c] = src[(size_t)(r0 + r)*D_ + c0 + c];
  }
  __syncthreads();
  for (int it = 0; it < 16; ++it){
    int idx = it*256 + threadIdx.x;
    int r = idx >> 6, c = idx & 63;
    dst[(size_t)(c0 + r)*D_ + r0 + c] = f2b(tile[c][r]);
  }
}

// Vb[b][n][D] (head cols) -> Vt[b*H+h][d][n]
__global__ void transpose_v(const unsigned short* __restrict__ Vb, unsigned short* __restrict__ Vt){
  __shared__ unsigned short tile[64*72];
  int nt = blockIdx.x, h = blockIdx.y, b = blockIdx.z;
  int n0 = nt*64, col0 = h*64;
  int tid = threadIdx.x;
  int r = tid >> 2, c16 = (tid & 3)*16;
  #pragma unroll
  for (int g = 0; g < 2; ++g){
    short8 v = *(const short8*)&Vb[((size_t)b*N_ + n0 + r)*D_ + col0 + c16 + g*8];
    #pragma unroll
    for (int e = 0; e < 8; ++e) tile[r*72 + c16 + g*8 + e] = (unsigned short)v[e];
  }
  __syncthreads();
  int d = tid >> 2, ng = (tid & 3)*16;
  short8 o0, o1;
  #pragma unroll
  for (int e = 0; e < 8; ++e){ o0[e] = (short)tile[(ng + e)*72 + d]; o1[e] = (short)tile[(ng + 8 + e)*72 + d]; }
  size_t ob = ((size_t)(b*H_ + h)*64 + d)*N_ + n0 + ng;
  *(short8*)&Vt[ob] = o0;
  *(short8*)&Vt[ob + 8] = o1;
}

// ---------------------------------------------------------------- GEMM, m97 structure (global_load_lds, BK=32)
template<int FINAL>
__launch_bounds__(256)
__global__ void gemm_bf16(const unsigned short* __restrict__ A, const unsigned short* __restrict__ Bt,
                          unsigned short* __restrict__ Cb, float* __restrict__ Cf,
                          const float* __restrict__ bias, int K, int Ncols){
  __shared__ __attribute__((aligned(16))) unsigned short As[128*32];
  __shared__ __attribute__((aligned(16))) unsigned short Bs[128*32];
  int tid = threadIdx.x, lane = tid & 63, wave = tid >> 6;
  int bm = blockIdx.x*128, bn = blockIdx.y*128;
  int wm = (wave >> 1)*64, wn = (wave & 1)*64;
  float4_ acc[4][4];
  #pragma unroll
  for (int i = 0; i < 4; ++i)
    #pragma unroll
    for (int j = 0; j < 4; ++j)
      #pragma unroll
      for (int r = 0; r < 4; ++r) acc[i][j][r] = 0.f;
  int srow = tid >> 2, scol = (tid & 3)*8;
  const unsigned short* a0 = &A[(size_t)(bm + srow)*K + scol];
  const unsigned short* a1 = &A[(size_t)(bm + 64 + srow)*K + scol];
  const unsigned short* b0 = &Bt[(size_t)(bn + srow)*K + scol];
  const unsigned short* b1 = &Bt[(size_t)(bn + 64 + srow)*K + scol];
  unsigned short* la0 = &As[tid*8];
  unsigned short* la1 = &As[2048 + tid*8];
  unsigned short* lb0 = &Bs[tid*8];
  unsigned short* lb1 = &Bs[2048 + tid*8];
  int kk = (lane >> 4)*8, l15 = lane & 15;
  for (int k0 = 0; k0 < K; k0 += 32){
    gl_lds16(a0, la0); gl_lds16(a1, la1);
    gl_lds16(b0, lb0); gl_lds16(b1, lb1);
    a0 += 32; a1 += 32; b0 += 32; b1 += 32;
    __syncthreads();
    short8 af[4], bf[4];
    #pragma unroll
    for (int i = 0; i < 4; ++i) af[i] = *(const short8*)&As[(wm + i*16 + l15)*32 + kk];
    #pragma unroll
    for (int j = 0; j < 4; ++j) bf[j] = *(const short8*)&Bs[(wn + j*16 + l15)*32 + kk];
    #pragma unroll
    for (int i = 0; i < 4; ++i)
      #pragma unroll
      for (int j = 0; j < 4; ++j)
        acc[i][j] = __builtin_amdgcn_mfma_f32_16x16x32_bf16(af[i], bf[j], acc[i][j], 0, 0, 0);
    __syncthreads();
  }
  int rr = (lane >> 4)*4, cc = l15;
  #pragma unroll
  for (int i = 0; i < 4; ++i)
    #pragma unroll
    for (int j = 0; j < 4; ++j)
      #pragma unroll
      for (int r = 0; r < 4; ++r){
        size_t row = bm + wm + i*16 + rr + r;
        int col = bn + wn + j*16 + cc;
        if (FINAL) Cf[row*Ncols + col] = acc[i][j][r] + bias[col];
        else       Cb[row*Ncols + col] = f2b(acc[i][j][r]);
      }
}

// ---------------------------------------------------------------- phi: Q pass (per-row stab, writes phiq[bh][n][m])
__launch_bounds__(256)
__global__ void phiq_kernel(const unsigned short* __restrict__ Qb, const unsigned short* __restrict__ projb,
                            unsigned short* __restrict__ phi){
  int tid = threadIdx.x, lane = tid & 63, wave = tid >> 6;
  int h = blockIdx.y, b = blockIdx.z;
  int n0 = blockIdx.x*64;
  int col0 = h*64;
  int kk = (lane >> 4)*8, l15 = lane & 15;
  size_t rowbase = (size_t)b*N_ + n0 + wave*16;
  short8 qa[2];
  #pragma unroll
  for (int ks = 0; ks < 2; ++ks)
    qa[ks] = *(const short8*)&Qb[(rowbase + l15)*D_ + col0 + ks*32 + kk];
  float s = 0.f;
  #pragma unroll
  for (int ks = 0; ks < 2; ++ks)
    #pragma unroll
    for (int j = 0; j < 8; ++j){ float q = b2f((unsigned short)qa[ks][j]); s += q*q; }
  s += __shfl_xor(s, 16, 64);
  s += __shfl_xor(s, 32, 64);
  s *= 0.0625f;
  float dg[4];
  #pragma unroll
  for (int r = 0; r < 4; ++r) dg[r] = __shfl(s, (lane & 48) | ((lane >> 4)*4 + r), 64);
  float4_ dd[16];
  #pragma unroll
  for (int mt = 0; mt < 16; ++mt){
    float4_ a; a[0]=a[1]=a[2]=a[3]=0.f;
    #pragma unroll
    for (int ks = 0; ks < 2; ++ks){
      short8 bfr = *(const short8*)&projb[(size_t)(mt*16 + l15)*DH_ + ks*32 + kk];
      a = __builtin_amdgcn_mfma_f32_16x16x32_bf16(qa[ks], bfr, a, 0, 0, 0);
    }
    dd[mt] = a;
  }
  size_t phibase = (size_t)(b*GH_ + h)*N_ + n0 + wave*16;
  #pragma unroll
  for (int r = 0; r < 4; ++r){
    float mx = dd[0][r];
    #pragma unroll
    for (int mt = 1; mt < 16; ++mt) mx = fmaxf(mx, dd[mt][r]);
    mx = fmaxf(mx, __shfl_xor(mx, 1, 64));
    mx = fmaxf(mx, __shfl_xor(mx, 2, 64));
    mx = fmaxf(mx, __shfl_xor(mx, 4, 64));
    mx = fmaxf(mx, __shfl_xor(mx, 8, 64));
    float sb = mx + dg[r];
    #pragma unroll
    for (int mt = 0; mt < 16; ++mt){
      float v = RATIO_*(__expf(dd[mt][r] - sb) + EPS_);
      phi[(phibase + (lane>>4)*4 + r)*M_ + mt*16 + l15] = f2b(v);
    }
  }
}

// phi: K max pass (global max -> stab)
__launch_bounds__(256)
__global__ void phik_max(const unsigned short* __restrict__ Kb, const unsigned short* __restrict__ projb,
                         unsigned int* __restrict__ stab_enc){
  int tid = threadIdx.x, lane = tid & 63, wave = tid >> 6;
  int h = blockIdx.y, b = blockIdx.z;
  int n0 = blockIdx.x*64;
  int col0 = h*64;
  int kk = (lane >> 4)*8, l15 = lane & 15;
  size_t rowbase = (size_t)b*N_ + n0 + wave*16;
  short8 qa[2];
  #pragma unroll
  for (int ks = 0; ks < 2; ++ks)
    qa[ks] = *(const short8*)&Kb[(rowbase + l15)*D_ + col0 + ks*32 + kk];
  float mx = -3e38f;
  #pragma unroll
  for (int mt = 0; mt < 16; ++mt){
    float4_ a; a[0]=a[1]=a[2]=a[3]=0.f;
    #pragma unroll
    for (int ks = 0; ks < 2; ++ks){
      short8 bfr = *(const short8*)&projb[(size_t)(mt*16 + l15)*DH_ + ks*32 + kk];
      a = __builtin_amdgcn_mfma_f32_16x16x32_bf16(qa[ks], bfr, a, 0, 0, 0);
    }
    #pragma unroll
    for (int r = 0; r < 4; ++r) mx = fmaxf(mx, a[r]);
  }
  #pragma unroll
  for (int m = 1; m < 64; m <<= 1) mx = fmaxf(mx, __shfl_xor(mx, m, 64));
  if (lane == 0) atomicMax(stab_enc, encf(mx));
}

// phi: K finish — recompute dd, exp, write phikT tiles [bh][nb][m=256][n=64] + fused ksum
__launch_bounds__(256)
__global__ void phik_finish(const unsigned short* __restrict__ Kb, const unsigned short* __restrict__ projb,
                            unsigned short* __restrict__ phikT, float* __restrict__ ksum,
                            const unsigned int* __restrict__ stab_enc){
  __shared__ __attribute__((aligned(16))) unsigned short pl[256*64];
  int tid = threadIdx.x, lane = tid & 63, wave = tid >> 6;
  int h = blockIdx.y, b = blockIdx.z, nb = blockIdx.x;
  int n0 = nb*64;
  int col0 = h*64;
  int kk = (lane >> 4)*8, l15 = lane & 15;
  int bh = b*GH_ + h;
  size_t rowbase = (size_t)b*N_ + n0 + wave*16;
  short8 qa[2];
  #pragma unroll
  for (int ks = 0; ks < 2; ++ks)
    qa[ks] = *(const short8*)&Kb[(rowbase + l15)*D_ + col0 + ks*32 + kk];
  float s = 0.f;
  #pragma unroll
  for (int ks = 0; ks < 2; ++ks)
    #pragma unroll
    for (int j = 0; j < 8; ++j){ float q = b2f((unsigned short)qa[ks][j]); s += q*q; }
  s += __shfl_xor(s, 16, 64);
  s += __shfl_xor(s, 32, 64);
  s *= 0.0625f;
  float stab = decf(*stab_enc);
  float dg[4];
  #pragma unroll
  for (int r = 0; r < 4; ++r) dg[r] = __shfl(s, (lane & 48) | ((lane >> 4)*4 + r), 64) + stab;
  #pragma unroll
  for (int mt = 0; mt < 16; ++mt){
    float4_ a; a[0]=a[1]=a[2]=a[3]=0.f;
    #pragma unroll
    for (int ks = 0; ks < 2; ++ks){
      short8 bfr = *(const short8*)&projb[(size_t)(mt*16 + l15)*DH_ + ks*32 + kk];
      a = __builtin_amdgcn_mfma_f32_16x16x32_bf16(qa[ks], bfr, a, 0, 0, 0);
    }
    int m = mt*16 + l15;
    #pragma unroll
    for (int r = 0; r < 4; ++r){
      float v = RATIO_*(__expf(a[r] - dg[r]) + EPS_);
      int n = wave*16 + (lane>>4)*4 + r;
      int slot = (n >> 3) ^ (m & 7);
      pl[m*64 + slot*8 + (n & 7)] = f2b(v);
    }
  }
  __syncthreads();
  int m = tid;
  float ssum = 0.f;
  size_t outbase = (((size_t)bh*64 + nb)*256 + m)*64;
  #pragma unroll
  for (int j = 0; j < 8; ++j){
    int slot = j ^ (m & 7);
    short8 v = *(const short8*)&pl[m*64 + slot*8];
    #pragma unroll
    for (int e = 0; e < 8; ++e) ssum += b2f((unsigned short)v[e]);
    *(short8*)&phikT[outbase + j*8] = v;
  }
  atomicAdd(&ksum[bh*M_ + m], ssum);
}

// ---------------------------------------------------------------- ctx partials: C[m][d] += phikT-chunk @ Vt-chunk
__launch_bounds__(256)
__global__ void ctx_kernel(const unsigned short* __restrict__ phikT, const unsigned short* __restrict__ Vt,
                           float* __restrict__ ctxp){
  int tid = threadIdx.x, lane = tid & 63, wave = tid >> 6;
  int split = blockIdx.x, h = blockIdx.y, b = blockIdx.z;
  int bh = b*GH_ + h;
  int kk = (lane >> 4)*8, l15 = lane & 15;
  float4_ acc[4][4];
  #pragma unroll
  for (int i = 0; i < 4; ++i)
    #pragma unroll
    for (int j = 0; j < 4; ++j)
      #pragma unroll
      for (int r = 0; r < 4; ++r) acc[i][j][r] = 0.f;
  const unsigned short* Abase = phikT + (size_t)bh*64*256*64;
  const unsigned short* Bbase = Vt + (size_t)(b*H_ + h)*64*N_;
  int n0 = split*256;
  #pragma unroll
  for (int ks = 0; ks < 8; ++ks){
    int n = n0 + ks*32;
    int nb = n >> 6, in0 = n & 32;
    short8 af[4], bf[4];
    #pragma unroll
    for (int mt = 0; mt < 4; ++mt)
      af[mt] = *(const short8*)&Abase[((size_t)nb*256 + wave*64 + mt*16 + l15)*64 + in0 + kk];
    #pragma unroll
    for (int dt = 0; dt < 4; ++dt)
      bf[dt] = *(const short8*)&Bbase[(size_t)(dt*16 + l15)*N_ + n + kk];
    #pragma unroll
    for (int mt = 0; mt < 4; ++mt)
      #pragma unroll
      for (int dt = 0; dt < 4; ++dt)
        acc[mt][dt] = __builtin_amdgcn_mfma_f32_16x16x32_bf16(af[mt], bf[dt], acc[mt][dt], 0, 0, 0);
  }
  int rr = (lane >> 4)*4;
  float* obase = ctxp + (((size_t)split*16 + bh)*256)*64;
  #pragma unroll
  for (int mt = 0; mt < 4; ++mt)
    #pragma unroll
    for (int dt = 0; dt < 4; ++dt)
      #pragma unroll
      for (int r = 0; r < 4; ++r)
        obase[(size_t)(wave*64 + mt*16 + rr + r)*64 + dt*16 + l15] = acc[mt][dt][r];
}

// reduce 16 splits -> ctxbT[bh][d][m] bf16
__global__ void ctx_reduce(const float* __restrict__ ctxp, unsigned short* __restrict__ ctxbT){
  __shared__ float tile[64*65];
  int mt = blockIdx.x, bh = blockIdx.y;
  int tid = threadIdx.x;
  #pragma unroll
  for (int i = 0; i < 16; ++i){
    int idx = i*256 + tid;
    int ml = idx >> 6, d = idx & 63;
    float s = 0.f;
    for (int sp = 0; sp < 16; ++sp)
      s += ctxp[(((size_t)sp*16 + bh)*256 + mt*64 + ml)*64 + d];
    tile[ml*65 + d] = s;
  }
  __syncthreads();
  int d = tid >> 2, m8 = (tid & 3)*16;
  short8 o0, o1;
  #pragma unroll
  for (int e = 0; e < 8; ++e){ o0[e] = (short)f2b(tile[(m8 + e)*65 + d]); o1[e] = (short)f2b(tile[(m8 + 8 + e)*65 + d]); }
  size_t ob = ((size_t)bh*64 + d)*256 + mt*64 + m8;
  *(short8*)&ctxbT[ob] = o0;
  *(short8*)&ctxbT[ob + 8] = o1;
}

// ---------------------------------------------------------------- out_g = (phi_q @ ctx) * d_inv
__launch_bounds__(256)
__global__ void outg_kernel(const unsigned short* __restrict__ phi_q, const unsigned short* __restrict__ ctxbT,
                            const float* __restrict__ k_sum, unsigned short* __restrict__ attnb){
  __shared__ float ks_l[256];
  __shared__ float dpart[64][4];
  __shared__ float dinv[64];
  int tid = threadIdx.x, lane = tid & 63, wave = tid >> 6;
  int h = blockIdx.y, b = blockIdx.z;
  int n0 = blockIdx.x*64;
  int bh = b*GH_ + h;
  ks_l[tid] = k_sum[bh*M_ + tid];
  __syncthreads();
  {
    int row = tid >> 2, q = tid & 3;
    const unsigned short* pr = &phi_q[((size_t)bh*N_ + n0 + row)*M_ + q*64];
    float s = 0.f;
    #pragma unroll
    for (int c = 0; c < 8; ++c){
      short8 v = *(const short8*)&pr[c*8];
      #pragma unroll
      for (int e = 0; e < 8; ++e) s += b2f((unsigned short)v[e])*ks_l[q*64 + c*8 + e];
    }
    dpart[row][q] = s;
  }
  __syncthreads();
  if (tid < 64) dinv[tid] = 1.f/(dpart[tid][0] + dpart[tid][1] + dpart[tid][2] + dpart[tid][3]);
  __syncthreads();
  int kk = (lane >> 4)*8, l15 = lane & 15;
  float4_ acc[4];
  #pragma unroll
  for (int dt = 0; dt < 4; ++dt){ acc[dt][0]=acc[dt][1]=acc[dt][2]=acc[dt][3]=0.f; }
  size_t arow = ((size_t)bh*N_ + n0 + wave*16 + l15)*M_;
  #pragma unroll
  for (int ks = 0; ks < 8; ++ks){
    short8 af = *(const short8*)&phi_q[arow + ks*32 + kk];
    #pragma unroll
    for (int dt = 0; dt < 4; ++dt){
      short8 bf = *(const short8*)&ctxbT[((size_t)bh*64 + dt*16 + l15)*M_ + ks*32 + kk];
      acc[dt] = __builtin_amdgcn_mfma_f32_16x16x32_bf16(af, bf, acc[dt], 0, 0, 0);
    }
  }
  int rr = (lane >> 4)*4;
  #pragma unroll
  for (int dt = 0; dt < 4; ++dt)
    #pragma unroll
    for (int r = 0; r < 4; ++r){
      int rloc = wave*16 + rr + r;
      float o = acc[dt][r]*dinv[rloc];
      attnb[((size_t)b*N_ + n0 + rloc)*D_ + h*64 + dt*16 + l15] = f2b(o);
    }
}

// ---------------------------------------------------------------- local windowed attention: 1 block per (window, head, b)
__launch_bounds__(512)
__global__ void local_attn_kernel(const unsigned short* __restrict__ Qb, const unsigned short* __restrict__ Kb,
                                  const unsigned short* __restrict__ Vt, unsigned short* __restrict__ attnb){
  __shared__ __attribute__((aligned(16))) unsigned short pl[8][32*64];
  int tid = threadIdx.x, lane = tid & 63, wv = tid >> 6;
  int w = blockIdx.x, hl = blockIdx.y, b = blockIdx.z;
  int col0 = (GH_ + hl)*64;
  int q0 = w*W_ + wv*32;
  int kk = (lane >> 4)*8, l15 = lane & 15;
  short8 qa[2][2];
  #pragma unroll
  for (int rt = 0; rt < 2; ++rt)
    #pragma unroll
    for (int ks = 0; ks < 2; ++ks)
      qa[rt][ks] = *(const short8*)&Qb[((size_t)b*N_ + q0 + rt*16 + l15)*D_ + col0 + ks*32 + kk];
  float m_r[2][4], l_r[2][4];
  float4_ accv[2][4];
  #pragma unroll
  for (int rt = 0; rt < 2; ++rt)
    #pragma unroll
    for (int r = 0; r < 4; ++r){ m_r[rt][r] = -1e30f; l_r[rt][r] = 0.f; }
  #pragma unroll
  for (int rt = 0; rt < 2; ++rt)
    #pragma unroll
    for (int dt = 0; dt < 4; ++dt){ accv[rt][dt][0]=accv[rt][dt][1]=accv[rt][dt][2]=accv[rt][dt][3]=0.f; }
  const unsigned short* Vrow = &Vt[(size_t)(b*H_ + GH_ + hl)*64*N_];
  unsigned short* plw = &pl[wv][0];
  for (int wi = w - 1; wi <= w + 1; ++wi){
    if (wi < 0 || wi >= NW_) continue;
    for (int c = 0; c < 4; ++c){
      int key0 = wi*W_ + c*64;
      float4_ s[2][4];
      #pragma unroll
      for (int rt = 0; rt < 2; ++rt)
        #pragma unroll
        for (int kt = 0; kt < 4; ++kt){ s[rt][kt][0]=s[rt][kt][1]=s[rt][kt][2]=s[rt][kt][3]=0.f; }
      #pragma unroll
      for (int ks = 0; ks < 2; ++ks)
        #pragma unroll
        for (int kt = 0; kt < 4; ++kt){
          short8 kb = *(const short8*)&Kb[((size_t)b*N_ + key0 + kt*16 + l15)*D_ + col0 + ks*32 + kk];
          #pragma unroll
          for (int rt = 0; rt < 2; ++rt)
            s[rt][kt] = __builtin_amdgcn_mfma_f32_16x16x32_bf16(qa[rt][ks], kb, s[rt][kt], 0, 0, 0);
        }
      #pragma unroll
      for (int rt = 0; rt < 2; ++rt)
        #pragma unroll
        for (int r = 0; r < 4; ++r){
          float sv0 = s[rt][0][r]*0.125f, sv1 = s[rt][1][r]*0.125f;
          float sv2 = s[rt][2][r]*0.125f, sv3 = s[rt][3][r]*0.125f;
          float mx = fmaxf(fmaxf(sv0, sv1), fmaxf(sv2, sv3));
          mx = fmaxf(mx, __shfl_xor(mx, 1, 64));
          mx = fmaxf(mx, __shfl_xor(mx, 2, 64));
          mx = fmaxf(mx, __shfl_xor(mx, 4, 64));
          mx = fmaxf(mx, __shfl_xor(mx, 8, 64));
          float mn = fmaxf(m_r[rt][r], mx);
          float al = __expf(m_r[rt][r] - mn);
          m_r[rt][r] = mn;
          float p0 = __expf(sv0 - mn), p1 = __expf(sv1 - mn);
          float p2 = __expf(sv2 - mn), p3 = __expf(sv3 - mn);
          float rs = p0 + p1 + p2 + p3;
          rs += __shfl_xor(rs, 1, 64);
          rs += __shfl_xor(rs, 2, 64);
          rs += __shfl_xor(rs, 4, 64);
          rs += __shfl_xor(rs, 8, 64);
          l_r[rt][r] = l_r[rt][r]*al + rs;
          #pragma unroll
          for (int dt = 0; dt < 4; ++dt) accv[rt][dt][r] *= al;
          int q = rt*16 + (lane>>4)*4 + r;
          int qm = (q & 7);
          pl[wv][q*64 + (((0*16 + l15) >> 3) ^ qm)*8 + (l15 & 7)] = f2b(p0);
          pl[wv][q*64 + (((1*16 + l15) >> 3) ^ qm)*8 + (l15 & 7)] = f2b(p1);
          pl[wv][q*64 + (((2*16 + l15) >> 3) ^ qm)*8 + (l15 & 7)] = f2b(p2);
          pl[wv][q*64 + (((3*16 + l15) >> 3) ^ qm)*8 + (l15 & 7)] = f2b(p3);
        }
      #pragma unroll
      for (int ks = 0; ks < 2; ++ks){
        short8 pa[2];
        #pragma unroll
        for (int rt = 0; rt < 2; ++rt){
          int qrow = rt*16 + l15;
          int slot = ((ks*4) + (lane >> 4)) ^ (qrow & 7);
          pa[rt] = *(const short8*)&plw[qrow*64 + slot*8];
        }
        #pragma unroll
        for (int dt = 0; dt < 4; ++dt){
          short8 vb = *(const short8*)&Vrow[(size_t)(dt*16 + l15)*N_ + key0 + ks*32 + kk];
          #pragma unroll
          for (int rt = 0; rt < 2; ++rt)
            accv[rt][dt] = __builtin_amdgcn_mfma_f32_16x16x32_bf16(pa[rt], vb, accv[rt][dt], 0, 0, 0);
        }
      }
    }
  }
  #pragma unroll
  for (int rt = 0; rt < 2; ++rt)
    #pragma unroll
    for (int dt = 0; dt < 4; ++dt)
      #pragma unroll
      for (int r = 0; r < 4; ++r){
        int qrow = q0 + rt*16 + (lane>>4)*4 + r;
        float o = accv[rt][dt][r]/l_r[rt][r];
        attnb[((size_t)b*N_ + qrow)*D_ + col0 + dt*16 + l15] = f2b(o);
      }
}

// ---------------------------------------------------------------- host launch
extern "C" void kernel_launch(void* const* d_in, const int* in_sizes, int n_in,
                              void* d_out, int out_size, void* d_ws, size_t ws_size,
                              hipStream_t stream){
  const float* x    = (const float*)d_in[0];
  const float* Wq   = (const float*)d_in[1];
  const float* Wk   = (const float*)d_in[2];
  const float* Wv   = (const float*)d_in[3];
  const float* Wo   = (const float*)d_in[4];
  const float* bo   = (const float*)d_in[5];
  const float* proj = (const float*)d_in[6];
  float* out = (float*)d_out;
  char* ws = (char*)d_ws;

  const size_t o_Wqt  = 0;
  const size_t o_Wkt  = o_Wqt  + (size_t)D_*D_*2;
  const size_t o_Wvt  = o_Wkt  + (size_t)D_*D_*2;
  const size_t o_Wot  = o_Wvt  + (size_t)D_*D_*2;
  const size_t o_Xb   = o_Wot  + (size_t)D_*D_*2;        // reused as attnb
  const size_t o_Qb   = o_Xb   + (size_t)R_*D_*2;
  const size_t o_Kb   = o_Qb   + (size_t)R_*D_*2;
  const size_t o_Vb   = o_Kb   + (size_t)R_*D_*2;
  const size_t o_Vt   = o_Vb   + (size_t)R_*D_*2;
  const size_t o_phiq = o_Vt   + (size_t)B_*H_*DH_*N_*2;
  const size_t o_phikT= o_phiq + (size_t)B_*GH_*N_*M_*2;
  const size_t o_ctxp = o_phikT+ (size_t)B_*GH_*N_*M_*2;
  const size_t o_ksum = o_ctxp + (size_t)16*B_*GH_*M_*DH_*4;
  const size_t o_ctxT = o_ksum + (size_t)B_*GH_*M_*4;
  const size_t o_projb= o_ctxT + (size_t)B_*GH_*DH_*M_*2;
  const size_t o_stab = o_projb+ (size_t)M_*DH_*2;

  unsigned short* Wqt  = (unsigned short*)(ws + o_Wqt);
  unsigned short* Wkt  = (unsigned short*)(ws + o_Wkt);
  unsigned short* Wvt  = (unsigned short*)(ws + o_Wvt);
  unsigned short* Wot  = (unsigned short*)(ws + o_Wot);
  unsigned short* Xb   = (unsigned short*)(ws + o_Xb);
  unsigned short* attnb= Xb;
  unsigned short* Qb   = (unsigned short*)(ws + o_Qb);
  unsigned short* Kb   = (unsigned short*)(ws + o_Kb);
  unsigned short* Vb   = (unsigned short*)(ws + o_Vb);
  unsigned short* Vt   = (unsigned short*)(ws + o_Vt);
  unsigned short* phiq = (unsigned short*)(ws + o_phiq);
  unsigned short* phikT= (unsigned short*)(ws + o_phikT);
  float*          ctxp = (float*)(ws + o_ctxp);
  float*          ksum = (float*)(ws + o_ksum);
  unsigned short* ctxT = (unsigned short*)(ws + o_ctxT);
  unsigned short* projb= (unsigned short*)(ws + o_projb);
  unsigned int*   stab = (unsigned int*)(ws + o_stab);

  (void)in_sizes; (void)n_in; (void)out_size; (void)ws_size;

  (void)hipMemsetAsync(ws + o_ksum, 0, (size_t)B_*GH_*M_*4, stream);
  init_misc<<<1, 1, 0, stream>>>(stab);
  cast_f32_bf16<<<R_*D_/8/256, 256, 0, stream>>>(x, Xb, R_*D_/8);
  cast_proj<<<64, 256, 0, stream>>>(proj, projb);
  transpose_w<<<dim3(16,16,4), 256, 0, stream>>>(Wq, Wk, Wv, Wo, Wqt, Wkt, Wvt, Wot);

  gemm_bf16<0><<<dim3(64,8), 256, 0, stream>>>(Xb, Wqt, Qb, nullptr, nullptr, D_, D_);
  gemm_bf16<0><<<dim3(64,8), 256, 0, stream>>>(Xb, Wkt, Kb, nullptr, nullptr, D_, D_);
  gemm_bf16<0><<<dim3(64,8), 256, 0, stream>>>(Xb, Wvt, Vb, nullptr, nullptr, D_, D_);

  transpose_v<<<dim3(64,16,2), 256, 0, stream>>>(Vb, Vt);

  phiq_kernel<<<dim3(64,8,2), 256, 0, stream>>>(Qb, projb, phiq);
  phik_max<<<dim3(64,8,2), 256, 0, stream>>>(Kb, projb, stab);
  phik_finish<<<dim3(64,8,2), 256, 0, stream>>>(Kb, projb, phikT, ksum, stab);

  ctx_kernel<<<dim3(16,8,2), 256, 0, stream>>>(phikT, Vt, ctxp);
  ctx_reduce<<<dim3(4,16), 256, 0, stream>>>(ctxp, ctxT);
  outg_kernel<<<dim3(64,8,2), 256, 0, stream>>>(phiq, ctxT, ksum, attnb);
  local_attn_kernel<<<dim3(16,8,2), 512, 0, stream>>>(Qb, Kb, Vt, attnb);

  gemm_bf16<1><<<dim3(64,8), 256, 0, stream>>>(attnb, Wot, nullptr, out, bo, D_, D_);
}